// Round 1
// baseline (1070.447 us; speedup 1.0000x reference)
//
#include <hip/hip_runtime.h>
#include <hip/hip_bf16.h>

#define BB 4
#define TT 4096
#define DD 2048
#define BOTC 256

typedef __bf16 bf16;
typedef __attribute__((ext_vector_type(8))) __bf16 bf16x8;
typedef __attribute__((ext_vector_type(4))) float f32x4;

constexpr int BM = 128, BN = 128, BK = 32;

__device__ __forceinline__ void async16(const void* g, bf16* l) {
  __builtin_amdgcn_global_load_lds((const __attribute__((address_space(1))) void*)g,
                                   (__attribute__((address_space(3))) void*)l, 16, 0, 0);
}

// C[m,n] = sum_k A[m,k]*B[n,k]  (both row-major, K contiguous)
// EPI 0: fp32 store. EPI 1: +bias[col], bf16 store. EPI 2: *scale, causal mask (col<=row-4 else -65000), bf16 store.
template <int EPI>
__global__ __launch_bounds__(256) void gemm_bt(
    const bf16* __restrict__ A, const bf16* __restrict__ Bm, void* __restrict__ Cout,
    const float* __restrict__ bias, int M, int N, int K,
    long sAb, long sBb, long sCb, float scale) {
  const int b = blockIdx.z;
  const int m0 = blockIdx.y * BM;
  const int n0 = blockIdx.x * BN;
  const int tid = threadIdx.x;
  const int lane = tid & 63;
  const int w = tid >> 6;
  const int wm = (w >> 1) * 64;
  const int wn = (w & 1) * 64;

  if (EPI == 2 && n0 > m0) {
    // fully-masked tile: tril(diag=-4) => all (i,j) with j > i-4. Since n0 >= m0+128 > m0+123.
    bf16* C = (bf16*)Cout + (size_t)b * sCb;
    bf16 neg = (bf16)(-65000.0f);
    bf16x8 v8 = {neg, neg, neg, neg, neg, neg, neg, neg};
#pragma unroll
    for (int it = 0; it < 8; ++it) {
      int c = it * 256 + tid;
      int row = c >> 4, cc = c & 15;
      *(bf16x8*)(C + (size_t)(m0 + row) * N + n0 + cc * 8) = v8;
    }
    return;
  }

  __shared__ bf16 As[BM * BK];
  __shared__ bf16 Bs[BN * BK];

  f32x4 acc[4][4] = {};

  const bf16* Arow = A + (size_t)b * sAb + (size_t)m0 * K;
  const bf16* Brow = Bm + (size_t)b * sBb + (size_t)n0 * K;

  for (int k0 = 0; k0 < K; k0 += BK) {
    // stage 128x32 bf16 A and B tiles: chunk c (16B) -> row=c>>2, kchunk=c&3; LDS row-major [128][32]
#pragma unroll
    for (int j = 0; j < 2; ++j) {
      int c = j * 256 + tid;
      int row = c >> 2, kc = c & 3;
      async16(Arow + (size_t)row * K + k0 + kc * 8, As + c * 8);
      async16(Brow + (size_t)row * K + k0 + kc * 8, Bs + c * 8);
    }
    __syncthreads();
    bf16x8 af[4], bfr[4];
#pragma unroll
    for (int mi = 0; mi < 4; ++mi)
      af[mi] = *(const bf16x8*)(As + (wm + mi * 16 + (lane & 15)) * BK + (lane >> 4) * 8);
#pragma unroll
    for (int ni = 0; ni < 4; ++ni)
      bfr[ni] = *(const bf16x8*)(Bs + (wn + ni * 16 + (lane & 15)) * BK + (lane >> 4) * 8);
#pragma unroll
    for (int mi = 0; mi < 4; ++mi)
#pragma unroll
      for (int ni = 0; ni < 4; ++ni)
        acc[mi][ni] = __builtin_amdgcn_mfma_f32_16x16x32_bf16(af[mi], bfr[ni], acc[mi][ni], 0, 0, 0);
    __syncthreads();
  }

  const int lcol = lane & 15;
  const int lrow = (lane >> 4) * 4;

  if (EPI == 0) {
    float* C = (float*)Cout + (size_t)b * sCb;
#pragma unroll
    for (int mi = 0; mi < 4; ++mi) {
      int rbase = m0 + wm + mi * 16 + lrow;
#pragma unroll
      for (int ni = 0; ni < 4; ++ni) {
        int col = n0 + wn + ni * 16 + lcol;
#pragma unroll
        for (int r = 0; r < 4; ++r)
          C[(size_t)(rbase + r) * N + col] = acc[mi][ni][r];
      }
    }
  } else if (EPI == 1) {
    bf16* C = (bf16*)Cout + (size_t)b * sCb;
#pragma unroll
    for (int mi = 0; mi < 4; ++mi) {
      int rbase = m0 + wm + mi * 16 + lrow;
#pragma unroll
      for (int ni = 0; ni < 4; ++ni) {
        int col = n0 + wn + ni * 16 + lcol;
        float bv = bias[col];
#pragma unroll
        for (int r = 0; r < 4; ++r)
          C[(size_t)(rbase + r) * N + col] = (bf16)(acc[mi][ni][r] + bv);
      }
    }
  } else {
    bf16* C = (bf16*)Cout + (size_t)b * sCb;
#pragma unroll
    for (int mi = 0; mi < 4; ++mi) {
      int rbase = m0 + wm + mi * 16 + lrow;
#pragma unroll
      for (int ni = 0; ni < 4; ++ni) {
        int col = n0 + wn + ni * 16 + lcol;
#pragma unroll
        for (int r = 0; r < 4; ++r) {
          int i = rbase + r;
          float v = acc[mi][ni][r] * scale;
          if (col > i - 4) v = -65000.0f;
          C[(size_t)i * N + col] = (bf16)v;
        }
      }
    }
  }
}

// fp32 [B,T,D] -> bf16 [B,T,D] and bf16 transposed [B,D,T]
__global__ __launch_bounds__(256) void conv_transpose(
    const float* __restrict__ hdc, bf16* __restrict__ hb, bf16* __restrict__ hT) {
  __shared__ float tile[32][33];
  int b = blockIdx.z;
  int d0 = blockIdx.x * 32, t0 = blockIdx.y * 32;
  int tx = threadIdx.x, ty = threadIdx.y;  // block (32,8)
  const float* src = hdc + (size_t)b * TT * DD;
  bf16* dstb = hb + (size_t)b * TT * DD;
  bf16* dstT = hT + (size_t)b * DD * TT;
#pragma unroll
  for (int rr = 0; rr < 32; rr += 8) {
    int r = ty + rr;
    float v = src[(size_t)(t0 + r) * DD + d0 + tx];
    tile[r][tx] = v;
    dstb[(size_t)(t0 + r) * DD + d0 + tx] = (bf16)v;
  }
  __syncthreads();
#pragma unroll
  for (int rr = 0; rr < 32; rr += 8) {
    int r = ty + rr;
    dstT[(size_t)(d0 + r) * TT + t0 + tx] = (bf16)tile[tx][r];
  }
}

__global__ __launch_bounds__(256) void conv_w(
    const float* __restrict__ Wq, const float* __restrict__ Wk,
    bf16* __restrict__ Wqb, bf16* __restrict__ Wkb) {
  int i = blockIdx.x * 256 + threadIdx.x;
  Wqb[i] = (bf16)Wq[i];
  Wkb[i] = (bf16)Wk[i];
}

// one block per row: softmax over S row (bf16, in-place) then combined = 0.7*decay + 0.3*softmax
__global__ __launch_bounds__(256) void softmax_combine(
    bf16* __restrict__ S, const float* __restrict__ decay) {
  int b = blockIdx.y, i = blockIdx.x;
  bf16* srow = S + ((size_t)b * TT + i) * TT;
  const float* drow = decay + ((size_t)b * TT + i) * TT;
  int t = threadIdx.x;
  int lane = t & 63, w = t >> 6;

  bf16x8 sv0 = *(const bf16x8*)(srow + (size_t)t * 8);
  bf16x8 sv1 = *(const bf16x8*)(srow + (size_t)(256 + t) * 8);
  float s[16];
#pragma unroll
  for (int e = 0; e < 8; ++e) { s[e] = (float)sv0[e]; s[8 + e] = (float)sv1[e]; }

  float m = s[0];
#pragma unroll
  for (int u = 1; u < 16; ++u) m = fmaxf(m, s[u]);
#pragma unroll
  for (int off = 32; off > 0; off >>= 1) m = fmaxf(m, __shfl_xor(m, off));
  __shared__ float redm[4], reds[4];
  if (lane == 0) redm[w] = m;
  __syncthreads();
  m = fmaxf(fmaxf(redm[0], redm[1]), fmaxf(redm[2], redm[3]));

  float p[16], sum = 0.f;
#pragma unroll
  for (int u = 0; u < 16; ++u) { p[u] = __expf(s[u] - m); sum += p[u]; }
#pragma unroll
  for (int off = 32; off > 0; off >>= 1) sum += __shfl_xor(sum, off);
  if (lane == 0) reds[w] = sum;
  __syncthreads();
  sum = reds[0] + reds[1] + reds[2] + reds[3];
  float inv = 0.3f / sum;

#pragma unroll
  for (int u = 0; u < 2; ++u) {
    int chunk = u * 256 + t;
    const float4* d4 = (const float4*)(drow + (size_t)chunk * 8);
    float4 da = d4[0], db = d4[1];
    bf16x8 o;
    o[0] = (bf16)(0.7f * da.x + p[u * 8 + 0] * inv);
    o[1] = (bf16)(0.7f * da.y + p[u * 8 + 1] * inv);
    o[2] = (bf16)(0.7f * da.z + p[u * 8 + 2] * inv);
    o[3] = (bf16)(0.7f * da.w + p[u * 8 + 3] * inv);
    o[4] = (bf16)(0.7f * db.x + p[u * 8 + 4] * inv);
    o[5] = (bf16)(0.7f * db.y + p[u * 8 + 5] * inv);
    o[6] = (bf16)(0.7f * db.z + p[u * 8 + 6] * inv);
    o[7] = (bf16)(0.7f * db.w + p[u * 8 + 7] * inv);
    *(bf16x8*)(srow + (size_t)chunk * 8) = o;
  }
}

extern "C" void kernel_launch(void* const* d_in, const int* in_sizes, int n_in,
                              void* d_out, int out_size, void* d_ws, size_t ws_size,
                              hipStream_t stream) {
  (void)in_sizes; (void)n_in; (void)out_size; (void)ws_size;
  const float* hdc = (const float*)d_in[0];
  const float* decay = (const float*)d_in[1];
  const float* Wq = (const float*)d_in[2];
  const float* bq = (const float*)d_in[3];
  const float* Wk = (const float*)d_in[4];
  const float* bk = (const float*)d_in[5];
  float* out = (float*)d_out;

  char* ws = (char*)d_ws;
  bf16* hdc_b = (bf16*)ws; ws += (size_t)BB * TT * DD * 2;
  bf16* hdcT  = (bf16*)ws; ws += (size_t)BB * TT * DD * 2;
  bf16* Wqb   = (bf16*)ws; ws += (size_t)BOTC * DD * 2;
  bf16* Wkb   = (bf16*)ws; ws += (size_t)BOTC * DD * 2;
  bf16* qb    = (bf16*)ws; ws += (size_t)BB * TT * BOTC * 2;
  bf16* kb    = (bf16*)ws; ws += (size_t)BB * TT * BOTC * 2;
  bf16* S     = (bf16*)ws; ws += (size_t)BB * TT * TT * 2;

  // 1) convert hdc to bf16 (+transposed copy); convert weights
  conv_transpose<<<dim3(DD / 32, TT / 32, BB), dim3(32, 8), 0, stream>>>(hdc, hdc_b, hdcT);
  conv_w<<<dim3(BOTC * DD / 256), 256, 0, stream>>>(Wq, Wk, Wqb, Wkb);

  // 2) projections: q = hdc@Wq^T + bq, k = hdc@Wk^T + bk   (M=B*T, N=256, K=2048)
  gemm_bt<1><<<dim3(BOTC / BN, (BB * TT) / BM, 1), 256, 0, stream>>>(
      hdc_b, Wqb, qb, bq, BB * TT, BOTC, DD, 0, 0, 0, 1.0f);
  gemm_bt<1><<<dim3(BOTC / BN, (BB * TT) / BM, 1), 256, 0, stream>>>(
      hdc_b, Wkb, kb, bk, BB * TT, BOTC, DD, 0, 0, 0, 1.0f);

  // 3) scores = (q@k^T)/16, masked (j<=i-4 else -65000), bf16   (per batch M=N=T, K=256)
  gemm_bt<2><<<dim3(TT / BN, TT / BM, BB), 256, 0, stream>>>(
      qb, kb, S, nullptr, TT, TT, BOTC,
      (long)TT * BOTC, (long)TT * BOTC, (long)TT * TT, 0.0625f);

  // 4) in-place: S <- 0.7*decay + 0.3*softmax(S)
  softmax_combine<<<dim3(TT, BB), 256, 0, stream>>>(S, decay);

  // 5) out = combined @ hdc  (per batch M=T, N=D, K=T; B-operand = hdcT rows)
  gemm_bt<0><<<dim3(DD / BN, TT / BM, BB), 256, 0, stream>>>(
      S, hdcT, out, nullptr, TT, DD, TT,
      (long)TT * TT, (long)DD * TT, (long)TT * DD, 1.0f);
}

// Round 2
// 986.501 us; speedup vs baseline: 1.0851x; 1.0851x over previous
//
#include <hip/hip_runtime.h>
#include <hip/hip_bf16.h>

#define BB 4
#define TT 4096
#define DD 2048
#define BOTC 256

typedef __bf16 bf16;
typedef __attribute__((ext_vector_type(4))) __bf16 bf16x4;
typedef __attribute__((ext_vector_type(8))) __bf16 bf16x8;
typedef __attribute__((ext_vector_type(4))) float f32x4;

constexpr int BM = 128, BN = 128, BK = 64;

__device__ __forceinline__ void async16(const void* g, bf16* l) {
  __builtin_amdgcn_global_load_lds((const __attribute__((address_space(1))) void*)g,
                                   (__attribute__((address_space(3))) void*)l, 16, 0, 0);
}

// C[m,n] = sum_k A[m,k]*B[n,k]  (row-major, K contiguous; ldA/ldB row strides)
// EPI 0: fp32 store. EPI 1: +bias[col], bf16 store.
// EPI 2: *scale, causal mask (col<=row-4 else -65000), bf16 store; fully-masked
//        tiles (n0>m0) return WITHOUT writing (softmax never reads them).
template <int EPI>
__global__ __launch_bounds__(256) void gemm_bt(
    const bf16* __restrict__ A, const bf16* __restrict__ Bm, void* __restrict__ Cout,
    const float* __restrict__ bias, int M, int N, int K, int ldA, int ldB,
    long sAb, long sBb, long sCb, float scale) {
  const int b = blockIdx.z;
  const int m0 = blockIdx.y * BM;
  const int n0 = blockIdx.x * BN;
  const int tid = threadIdx.x;
  const int lane = tid & 63;
  const int w = tid >> 6;
  const int wm = (w >> 1) * 64;
  const int wn = (w & 1) * 64;

  if (EPI == 2 && n0 > m0) return;  // fully masked: never written, never read

  __shared__ bf16 As[BM * BK];
  __shared__ bf16 Bs[BN * BK];

  f32x4 acc[4][4] = {};

  const bf16* Arow = A + (size_t)b * sAb + (size_t)m0 * ldA;
  const bf16* Brow = Bm + (size_t)b * sBb + (size_t)n0 * ldB;

  for (int k0 = 0; k0 < K; k0 += BK) {
    // stage 128x64 bf16 tiles; 16B chunk c -> row=c>>3, lds k-chunk=c&7,
    // global k-chunk = (c&7) ^ (row&7)  (XOR swizzle kills frag-read bank conflicts)
#pragma unroll
    for (int j = 0; j < 4; ++j) {
      int c = j * 256 + tid;
      int row = c >> 3, kc = c & 7;
      int gk = kc ^ (row & 7);
      async16(Arow + (size_t)row * ldA + k0 + gk * 8, As + (size_t)c * 8);
      async16(Brow + (size_t)row * ldB + k0 + gk * 8, Bs + (size_t)c * 8);
    }
    __syncthreads();
    bf16x8 af[4][2], bfr[4][2];
#pragma unroll
    for (int mi = 0; mi < 4; ++mi)
#pragma unroll
      for (int kk = 0; kk < 2; ++kk) {
        int row = wm + mi * 16 + (lane & 15);
        int kc = kk * 4 + (lane >> 4);
        af[mi][kk] = *(const bf16x8*)(As + ((size_t)row * 8 + (kc ^ (row & 7))) * 8);
      }
#pragma unroll
    for (int ni = 0; ni < 4; ++ni)
#pragma unroll
      for (int kk = 0; kk < 2; ++kk) {
        int row = wn + ni * 16 + (lane & 15);
        int kc = kk * 4 + (lane >> 4);
        bfr[ni][kk] = *(const bf16x8*)(Bs + ((size_t)row * 8 + (kc ^ (row & 7))) * 8);
      }
#pragma unroll
    for (int kk = 0; kk < 2; ++kk)
#pragma unroll
      for (int mi = 0; mi < 4; ++mi)
#pragma unroll
        for (int ni = 0; ni < 4; ++ni)
          acc[mi][ni] = __builtin_amdgcn_mfma_f32_16x16x32_bf16(af[mi][kk], bfr[ni][kk], acc[mi][ni], 0, 0, 0);
    __syncthreads();
  }

  const int lcol = lane & 15;
  const int lrow = (lane >> 4) * 4;

  if (EPI == 0) {
    float* C = (float*)Cout + (size_t)b * sCb;
#pragma unroll
    for (int mi = 0; mi < 4; ++mi) {
      int rbase = m0 + wm + mi * 16 + lrow;
#pragma unroll
      for (int ni = 0; ni < 4; ++ni) {
        int col = n0 + wn + ni * 16 + lcol;
#pragma unroll
        for (int r = 0; r < 4; ++r)
          C[(size_t)(rbase + r) * N + col] = acc[mi][ni][r];
      }
    }
  } else if (EPI == 1) {
    bf16* C = (bf16*)Cout + (size_t)b * sCb;
#pragma unroll
    for (int mi = 0; mi < 4; ++mi) {
      int rbase = m0 + wm + mi * 16 + lrow;
#pragma unroll
      for (int ni = 0; ni < 4; ++ni) {
        int col = n0 + wn + ni * 16 + lcol;
        float bv = bias[col];
#pragma unroll
        for (int r = 0; r < 4; ++r)
          C[(size_t)(rbase + r) * N + col] = (bf16)(acc[mi][ni][r] + bv);
      }
    }
  } else {
    bf16* C = (bf16*)Cout + (size_t)b * sCb;
#pragma unroll
    for (int mi = 0; mi < 4; ++mi) {
      int rbase = m0 + wm + mi * 16 + lrow;
#pragma unroll
      for (int ni = 0; ni < 4; ++ni) {
        int col = n0 + wn + ni * 16 + lcol;
#pragma unroll
        for (int r = 0; r < 4; ++r) {
          int i = rbase + r;
          float v = acc[mi][ni][r] * scale;
          if (col > i - 4) v = -65000.0f;
          C[(size_t)i * N + col] = (bf16)v;
        }
      }
    }
  }
}

// fp32 [B,T,D] -> bf16 [B,T,D] and bf16 transposed [B,D,T], 64x64 tiles, wide stores
__global__ __launch_bounds__(256) void conv_transpose(
    const float* __restrict__ hdc, bf16* __restrict__ hb, bf16* __restrict__ hT) {
  __shared__ float tile[64][65];
  int b = blockIdx.z;
  int d0 = blockIdx.x * 64, t0 = blockIdx.y * 64;
  int tid = threadIdx.x;
  const float* src = hdc + (size_t)b * TT * DD;
  bf16* dstb = hb + (size_t)b * TT * DD;
  bf16* dstT = hT + (size_t)b * DD * TT;
  int c4 = tid & 15, r0 = tid >> 4;
#pragma unroll
  for (int rr = 0; rr < 4; ++rr) {
    int r = rr * 16 + r0;
    float4 v = *(const float4*)(src + (size_t)(t0 + r) * DD + d0 + c4 * 4);
    tile[r][c4 * 4 + 0] = v.x;
    tile[r][c4 * 4 + 1] = v.y;
    tile[r][c4 * 4 + 2] = v.z;
    tile[r][c4 * 4 + 3] = v.w;
    bf16x4 o;
    o[0] = (bf16)v.x; o[1] = (bf16)v.y; o[2] = (bf16)v.z; o[3] = (bf16)v.w;
    *(bf16x4*)(dstb + (size_t)(t0 + r) * DD + d0 + c4 * 4) = o;
  }
  __syncthreads();
  int tc = tid & 7, dr0 = tid >> 3;
#pragma unroll
  for (int rr = 0; rr < 2; ++rr) {
    int dr = rr * 32 + dr0;
    bf16x8 o;
#pragma unroll
    for (int e = 0; e < 8; ++e) o[e] = (bf16)tile[tc * 8 + e][dr];
    *(bf16x8*)(dstT + (size_t)(d0 + dr) * TT + t0 + tc * 8) = o;
  }
}

// Wq,Wk fp32 [256,2048] -> stacked bf16 [512,2048]; bq,bk -> bqk fp32[512]
__global__ __launch_bounds__(256) void conv_w(
    const float* __restrict__ Wq, const float* __restrict__ Wk,
    const float* __restrict__ bq, const float* __restrict__ bk,
    bf16* __restrict__ Wqkb, float* __restrict__ bqk) {
  int i = blockIdx.x * 256 + threadIdx.x;
  float4 q = *(const float4*)(Wq + (size_t)i * 4);
  float4 k = *(const float4*)(Wk + (size_t)i * 4);
  bf16x4 qo, ko;
  qo[0] = (bf16)q.x; qo[1] = (bf16)q.y; qo[2] = (bf16)q.z; qo[3] = (bf16)q.w;
  ko[0] = (bf16)k.x; ko[1] = (bf16)k.y; ko[2] = (bf16)k.z; ko[3] = (bf16)k.w;
  *(bf16x4*)(Wqkb + (size_t)i * 4) = qo;
  *(bf16x4*)(Wqkb + (size_t)BOTC * DD + (size_t)i * 4) = ko;
  if (blockIdx.x == 0) {
    bqk[threadIdx.x] = bq[threadIdx.x];
    bqk[256 + threadIdx.x] = bk[threadIdx.x];
  }
}

// one block per row i: softmax over valid prefix (j < i-3) of S (bf16), then
// write combined = 0.7*decay + 0.3*softmax over the FULL row (masked region
// contributes exactly 0 in fp32; rows i<4 are uniform 1/4096 like the reference).
__global__ __launch_bounds__(256) void softmax_combine(
    bf16* __restrict__ S, const float* __restrict__ decay) {
  int b = blockIdx.y, i = blockIdx.x;
  bf16* srow = S + ((size_t)b * TT + i) * TT;
  const float* drow = decay + ((size_t)b * TT + i) * TT;
  int t = threadIdx.x;
  int lane = t & 63, w = t >> 6;
  const int valid = i - 3;  // j < valid are allowed
  const int nc = valid > 0 ? (valid + 7) >> 3 : 0;  // chunks containing valid elems

  float p[2][8];
  float inv = 0.f, pc = 0.f;

  if (valid > 0) {
    float s[2][8];
#pragma unroll
    for (int u = 0; u < 2; ++u) {
      int c = u * 256 + t;
      if (c < nc) {
        bf16x8 sv = *(const bf16x8*)(srow + (size_t)c * 8);
#pragma unroll
        for (int e = 0; e < 8; ++e) {
          int j = c * 8 + e;
          s[u][e] = j < valid ? (float)sv[e] : -INFINITY;
        }
      } else {
#pragma unroll
        for (int e = 0; e < 8; ++e) s[u][e] = -INFINITY;
      }
    }
    float m = s[0][0];
#pragma unroll
    for (int u = 0; u < 2; ++u)
#pragma unroll
      for (int e = 0; e < 8; ++e) m = fmaxf(m, s[u][e]);
#pragma unroll
    for (int off = 32; off > 0; off >>= 1) m = fmaxf(m, __shfl_xor(m, off));
    __shared__ float redm[4], reds[4];
    if (lane == 0) redm[w] = m;
    __syncthreads();
    m = fmaxf(fmaxf(redm[0], redm[1]), fmaxf(redm[2], redm[3]));

    float sum = 0.f;
#pragma unroll
    for (int u = 0; u < 2; ++u)
#pragma unroll
      for (int e = 0; e < 8; ++e) {
        p[u][e] = __expf(s[u][e] - m);
        sum += p[u][e];
      }
#pragma unroll
    for (int off = 32; off > 0; off >>= 1) sum += __shfl_xor(sum, off);
    if (lane == 0) reds[w] = sum;
    __syncthreads();
    sum = reds[0] + reds[1] + reds[2] + reds[3];
    inv = 0.3f / sum;
  } else {
    pc = 0.3f / 4096.0f;  // all-masked row: softmax is uniform 1/4096
#pragma unroll
    for (int u = 0; u < 2; ++u)
#pragma unroll
      for (int e = 0; e < 8; ++e) p[u][e] = 0.f;
  }

#pragma unroll
  for (int u = 0; u < 2; ++u) {
    int c = u * 256 + t;
    const float4* d4 = (const float4*)(drow + (size_t)c * 8);
    float4 da = d4[0], db = d4[1];
    float pv[8];
#pragma unroll
    for (int e = 0; e < 8; ++e) pv[e] = p[u][e] * inv + pc;
    bf16x8 o;
    o[0] = (bf16)(0.7f * da.x + pv[0]);
    o[1] = (bf16)(0.7f * da.y + pv[1]);
    o[2] = (bf16)(0.7f * da.z + pv[2]);
    o[3] = (bf16)(0.7f * da.w + pv[3]);
    o[4] = (bf16)(0.7f * db.x + pv[4]);
    o[5] = (bf16)(0.7f * db.y + pv[5]);
    o[6] = (bf16)(0.7f * db.z + pv[6]);
    o[7] = (bf16)(0.7f * db.w + pv[7]);
    *(bf16x8*)(srow + (size_t)c * 8) = o;
  }
}

extern "C" void kernel_launch(void* const* d_in, const int* in_sizes, int n_in,
                              void* d_out, int out_size, void* d_ws, size_t ws_size,
                              hipStream_t stream) {
  (void)in_sizes; (void)n_in; (void)out_size; (void)ws_size;
  const float* hdc = (const float*)d_in[0];
  const float* decay = (const float*)d_in[1];
  const float* Wq = (const float*)d_in[2];
  const float* bq = (const float*)d_in[3];
  const float* Wk = (const float*)d_in[4];
  const float* bk = (const float*)d_in[5];
  float* out = (float*)d_out;

  char* ws = (char*)d_ws;
  bf16* hdc_b = (bf16*)ws; ws += (size_t)BB * TT * DD * 2;
  bf16* hdcT  = (bf16*)ws; ws += (size_t)BB * TT * DD * 2;
  bf16* Wqkb  = (bf16*)ws; ws += (size_t)2 * BOTC * DD * 2;
  float* bqk  = (float*)ws; ws += 2 * BOTC * 4;
  bf16* qk    = (bf16*)ws; ws += (size_t)BB * TT * 2 * BOTC * 2;
  bf16* S     = (bf16*)ws; ws += (size_t)BB * TT * TT * 2;

  // 1) hdc -> bf16 (+transposed); weights -> stacked bf16 + bias vec
  conv_transpose<<<dim3(DD / 64, TT / 64, BB), 256, 0, stream>>>(hdc, hdc_b, hdcT);
  conv_w<<<dim3(BOTC * DD / 1024), 256, 0, stream>>>(Wq, Wk, bq, bk, Wqkb, bqk);

  // 2) fused projection: [q|k] = hdc @ [Wq;Wk]^T + [bq;bk]   (M=B*T, N=512, K=2048)
  gemm_bt<1><<<dim3((2 * BOTC) / BN, (BB * TT) / BM, 1), 256, 0, stream>>>(
      hdc_b, Wqkb, qk, bqk, BB * TT, 2 * BOTC, DD, DD, DD, 0, 0, 0, 1.0f);

  // 3) scores = (q@k^T)/16 masked, bf16; masked tiles skipped entirely
  gemm_bt<2><<<dim3(TT / BN, TT / BM, BB), 256, 0, stream>>>(
      qk, qk + BOTC, S, nullptr, TT, TT, BOTC, 2 * BOTC, 2 * BOTC,
      (long)TT * 2 * BOTC, (long)TT * 2 * BOTC, (long)TT * TT, 0.0625f);

  // 4) in-place: S <- 0.7*decay + 0.3*softmax(S)  (prefix-only read)
  softmax_combine<<<dim3(TT, BB), 256, 0, stream>>>(S, decay);

  // 5) out = combined @ hdc  (per batch M=T, N=D, K=T)
  gemm_bt<0><<<dim3(DD / BN, TT / BM, BB), 256, 0, stream>>>(
      S, hdcT, out, nullptr, TT, DD, TT, TT, TT,
      (long)TT * TT, (long)DD * TT, (long)TT * DD, 1.0f);
}